// Round 21
// baseline (618.419 us; speedup 1.0000x reference)
//
#include <hip/hip_runtime.h>
#include <cstdint>
#include <cstddef>

#define DM   2048
#define NH   16
#define HD   128
#define DFF  8192
#define SEQ  2048
#define NB   2
#define NTOK (NB * SEQ)

using bf16x8 = __attribute__((ext_vector_type(8))) __bf16;
using f32x4  = __attribute__((ext_vector_type(4))) float;

__device__ __forceinline__ unsigned short f2bf(float f) {
  unsigned int u = __float_as_uint(f);
  u += 0x7fffu + ((u >> 16) & 1u);
  return (unsigned short)(u >> 16);
}
__device__ __forceinline__ float bf2f(unsigned short u) {
  return __uint_as_float((unsigned int)u << 16);
}

__device__ __forceinline__ void gload16(const void* g, void* l) {
  __builtin_amdgcn_global_load_lds(
      (const __attribute__((address_space(1))) unsigned int*)g,
      (__attribute__((address_space(3))) unsigned int*)l, 16, 0, 0);
}

__device__ __forceinline__ f32x4 mfma16(bf16x8 a, bf16x8 b, f32x4 c) {
  return __builtin_amdgcn_mfma_f32_16x16x32_bf16(a, b, c, 0, 0, 0);
}

#define BARRIER() asm volatile("s_barrier" ::: "memory")
#define LGKM0()   asm volatile("s_waitcnt lgkmcnt(0)" ::: "memory")

// XCD swizzle: kept ONLY for attention (chunk of 64 blocks = 4 whole heads =
// 4 MB K/V per XCD L2). On GEMMs it duplicated B across XCDs -> natural order.
__device__ __forceinline__ int xcd_swz(int hb, int nwg) {
  return (hb & 7) * (nwg >> 3) + (hb >> 3);
}

// ---------------- transpose + cast fp32 -> bf16, 64x64 tiles ----------------
__device__ __forceinline__ void tc64_body(
    const float* __restrict__ src, unsigned short* __restrict__ dst,
    int R, int C, int r0, int c0) {
  __shared__ float tile[64][65];
  const int t = threadIdx.x;
#pragma unroll
  for (int j = 0; j < 4; ++j) {
    const int c = t + j * 256;
    const int row = c >> 4, col = (c & 15) * 4;
    float4 v = *(const float4*)(src + (size_t)(r0 + row) * C + c0 + col);
    tile[row][col] = v.x; tile[row][col + 1] = v.y;
    tile[row][col + 2] = v.z; tile[row][col + 3] = v.w;
  }
  __syncthreads();
#pragma unroll
  for (int j = 0; j < 4; ++j) {
    const int c = t + j * 256;
    const int drow = c >> 4, scol = (c & 15) * 4;
    union { unsigned short u[4]; ushort4 v; } pk;
    pk.u[0] = f2bf(tile[scol][drow]);
    pk.u[1] = f2bf(tile[scol + 1][drow]);
    pk.u[2] = f2bf(tile[scol + 2][drow]);
    pk.u[3] = f2bf(tile[scol + 3][drow]);
    *(ushort4*)(dst + (size_t)(c0 + drow) * R + r0 + scol) = pk.v;
  }
}

__global__ __launch_bounds__(256) void transpose_cast(
    const float* __restrict__ src, unsigned short* __restrict__ dst, int R, int C) {
  tc64_body(src, dst, R, C, blockIdx.y * 64, blockIdx.x * 64);
}

__global__ __launch_bounds__(256) void transpose_cast4(
    const float* __restrict__ wq, const float* __restrict__ wk,
    const float* __restrict__ wv, const float* __restrict__ wo,
    unsigned short* __restrict__ dqkv, unsigned short* __restrict__ dwo) {
  const int z = blockIdx.z;
  const float* src = (z == 0) ? wq : (z == 1) ? wk : (z == 2) ? wv : wo;
  unsigned short* dst = (z < 3) ? (dqkv + (size_t)z * 2048 * 2048) : dwo;
  tc64_body(src, dst, 2048, 2048, blockIdx.y * 64, blockIdx.x * 64);
}

// ---------------- layernorm fp32 -> bf16 ------------------------------------
__global__ __launch_bounds__(256) void ln_kernel(
    const float* __restrict__ x, const float* __restrict__ gam,
    const float* __restrict__ bet, unsigned short* __restrict__ out) {
  const int row = blockIdx.x, tid = threadIdx.x;
  const float* xr = x + (size_t)row * DM;
  float4 a = *(const float4*)(xr + tid * 8);
  float4 b = *(const float4*)(xr + tid * 8 + 4);
  float s  = a.x + a.y + a.z + a.w + b.x + b.y + b.z + b.w;
  float s2 = a.x*a.x + a.y*a.y + a.z*a.z + a.w*a.w +
             b.x*b.x + b.y*b.y + b.z*b.z + b.w*b.w;
#pragma unroll
  for (int off = 32; off > 0; off >>= 1) {
    s  += __shfl_xor(s, off);
    s2 += __shfl_xor(s2, off);
  }
  __shared__ float red[8];
  const int wid = tid >> 6;
  if ((tid & 63) == 0) { red[wid] = s; red[4 + wid] = s2; }
  __syncthreads();
  s  = red[0] + red[1] + red[2] + red[3];
  s2 = red[4] + red[5] + red[6] + red[7];
  const float mean = s * (1.0f / DM);
  const float var  = s2 * (1.0f / DM) - mean * mean;
  const float rstd = rsqrtf(var + 1e-5f);
  float4 g0 = *(const float4*)(gam + tid * 8);
  float4 g1 = *(const float4*)(gam + tid * 8 + 4);
  float4 e0 = *(const float4*)(bet + tid * 8);
  float4 e1 = *(const float4*)(bet + tid * 8 + 4);
  union { unsigned short u[8]; uint4 v; } pk;
  const float* av = (const float*)&a; const float* bv = (const float*)&b;
  const float* gv0 = (const float*)&g0; const float* gv1 = (const float*)&g1;
  const float* ev0 = (const float*)&e0; const float* ev1 = (const float*)&e1;
#pragma unroll
  for (int j = 0; j < 4; j++) pk.u[j]     = f2bf((av[j] - mean) * rstd * gv0[j] + ev0[j]);
#pragma unroll
  for (int j = 0; j < 4; j++) pk.u[4 + j] = f2bf((bv[j] - mean) * rstd * gv1[j] + ev1[j]);
  *(uint4*)(out + (size_t)row * DM + tid * 8) = pk.v;
}

// ---------------- layernorm bf16 -> bf16 (x2 residual stream) ---------------
__global__ __launch_bounds__(256) void ln_kernel_b(
    const unsigned short* __restrict__ x, const float* __restrict__ gam,
    const float* __restrict__ bet, unsigned short* __restrict__ out) {
  const int row = blockIdx.x, tid = threadIdx.x;
  const unsigned short* xr = x + (size_t)row * DM;
  union { unsigned short u[8]; uint4 v; } in;
  in.v = *(const uint4*)(xr + tid * 8);
  float xv[8];
#pragma unroll
  for (int j = 0; j < 8; ++j) xv[j] = bf2f(in.u[j]);
  float s = 0.f, s2 = 0.f;
#pragma unroll
  for (int j = 0; j < 8; ++j) { s += xv[j]; s2 += xv[j] * xv[j]; }
#pragma unroll
  for (int off = 32; off > 0; off >>= 1) {
    s  += __shfl_xor(s, off);
    s2 += __shfl_xor(s2, off);
  }
  __shared__ float red[8];
  const int wid = tid >> 6;
  if ((tid & 63) == 0) { red[wid] = s; red[4 + wid] = s2; }
  __syncthreads();
  s  = red[0] + red[1] + red[2] + red[3];
  s2 = red[4] + red[5] + red[6] + red[7];
  const float mean = s * (1.0f / DM);
  const float var  = s2 * (1.0f / DM) - mean * mean;
  const float rstd = rsqrtf(var + 1e-5f);
  float4 g0 = *(const float4*)(gam + tid * 8);
  float4 g1 = *(const float4*)(gam + tid * 8 + 4);
  float4 e0 = *(const float4*)(bet + tid * 8);
  float4 e1 = *(const float4*)(bet + tid * 8 + 4);
  const float* gv0 = (const float*)&g0; const float* gv1 = (const float*)&g1;
  const float* ev0 = (const float*)&e0; const float* ev1 = (const float*)&e1;
  union { unsigned short u[8]; uint4 v; } pk;
#pragma unroll
  for (int j = 0; j < 4; j++) pk.u[j]     = f2bf((xv[j] - mean) * rstd * gv0[j] + ev0[j]);
#pragma unroll
  for (int j = 0; j < 4; j++) pk.u[4 + j] = f2bf((xv[4 + j] - mean) * rstd * gv1[j] + ev1[j]);
  *(uint4*)(out + (size_t)row * DM + tid * 8) = pk.v;
}

// ======== 256x256 8-phase GEMM v2 (best measured: 175 us / 790 TF on FFN1) ==
template <int EPI>
__global__ __launch_bounds__(512, 2) void gemm256(
    const unsigned short* __restrict__ A, const unsigned short* __restrict__ Bt,
    int M, int N, int K,
    unsigned short* __restrict__ o0, unsigned short* __restrict__ o1,
    unsigned short* __restrict__ o2, float* __restrict__ fo,
    const float* __restrict__ e0, const float* __restrict__ e1) {
  __shared__ __attribute__((aligned(16))) unsigned short As[2][256 * 64];
  __shared__ __attribute__((aligned(16))) unsigned short Bs[2][256 * 64];
  const int tid = threadIdx.x;
  const int wid = tid >> 6, lane = tid & 63;
  const int wr = wid >> 2, wc = wid & 3;
  const int c16 = lane & 15, g = lane >> 4;
  const int m0 = blockIdx.y * 256, n0 = blockIdx.x * 256;

  const int c0 = tid, c1 = tid + 512;
  const int r0_ = c0 >> 3, s0_ = ((c0 & 7) ^ (r0_ & 7)) * 8;
  const int r1_ = c1 >> 3, s1_ = ((c1 & 7) ^ (r1_ & 7)) * 8;
  const unsigned short* a0p = A + (size_t)(m0 + r0_) * K + s0_;
  const unsigned short* a1p = A + (size_t)(m0 + r1_) * K + s1_;
  const unsigned short* b0p = Bt + (size_t)(n0 + r0_) * K + s0_;
  const unsigned short* b1p = Bt + (size_t)(n0 + r1_) * K + s1_;
  const size_t hstep = (size_t)128 * K;

  auto SA = [&](int buf, int h, int kt) {
    gload16(a0p + h * hstep + kt * 64, &As[buf][h * 8192 + c0 * 8]);
    gload16(a1p + h * hstep + kt * 64, &As[buf][h * 8192 + c1 * 8]);
  };
  auto SB = [&](int buf, int h, int kt) {
    gload16(b0p + h * hstep + kt * 64, &Bs[buf][h * 8192 + c0 * 8]);
    gload16(b1p + h * hstep + kt * 64, &Bs[buf][h * 8192 + c1 * 8]);
  };

  const int swz   = (c16 & 7) << 4;
  const int k0off = (g * 16) ^ swz;
  const int k1off = (64 + g * 16) ^ swz;

  f32x4 acc[8][4];
#pragma unroll
  for (int i = 0; i < 8; i++)
#pragma unroll
    for (int j = 0; j < 4; j++) acc[i][j] = f32x4{0.f, 0.f, 0.f, 0.f};

  bf16x8 af0[4][2], af1[4][2], bf0[2][2], bf1[2][2];

  const int NT = K >> 6;
  SA(0, 0, 0); SA(0, 1, 0); SB(0, 0, 0); SB(0, 1, 0);
  SB(1, 0, 1); SB(1, 1, 1); SA(1, 0, 1);
  asm volatile("s_waitcnt vmcnt(6)" ::: "memory");
  BARRIER();

  for (int t = 0; t < NT; ++t) {
    const int buf = t & 1;
    const char* Ac = (const char*)As[buf];
    const char* Bc = (const char*)Bs[buf];
    const bool st = (t + 2) < NT;
    // P1: read A strip0 + B strip0 ; stage A1(t+1) -> buf^1 ; MFMA (s0,s0)
#pragma unroll
    for (int mi = 0; mi < 4; ++mi) {
      const int rb = (wr * 64 + mi * 16 + c16) * 128;
      af0[mi][0] = *(const bf16x8*)(Ac + rb + k0off);
      af0[mi][1] = *(const bf16x8*)(Ac + rb + k1off);
    }
#pragma unroll
    for (int ni = 0; ni < 2; ++ni) {
      const int rb = (wc * 32 + ni * 16 + c16) * 128;
      bf0[ni][0] = *(const bf16x8*)(Bc + rb + k0off);
      bf0[ni][1] = *(const bf16x8*)(Bc + rb + k1off);
    }
    if (t + 1 < NT) SA(buf ^ 1, 1, t + 1);
    BARRIER(); LGKM0();
    __builtin_amdgcn_s_setprio(1);
#pragma unroll
    for (int mi = 0; mi < 4; ++mi)
#pragma unroll
      for (int ni = 0; ni < 2; ++ni)
#pragma unroll
        for (int kk = 0; kk < 2; ++kk)
          acc[mi][ni] = mfma16(af0[mi][kk], bf0[ni][kk], acc[mi][ni]);
    __builtin_amdgcn_s_setprio(0);
    BARRIER();
    // P2: read B strip1 ; stage B0(t+2) ; MFMA (s0,s1)
#pragma unroll
    for (int ni = 0; ni < 2; ++ni) {
      const int rb = (128 + wc * 32 + ni * 16 + c16) * 128;
      bf1[ni][0] = *(const bf16x8*)(Bc + rb + k0off);
      bf1[ni][1] = *(const bf16x8*)(Bc + rb + k1off);
    }
    if (st) SB(buf, 0, t + 2);
    BARRIER(); LGKM0();
    __builtin_amdgcn_s_setprio(1);
#pragma unroll
    for (int mi = 0; mi < 4; ++mi)
#pragma unroll
      for (int ni = 0; ni < 2; ++ni)
#pragma unroll
        for (int kk = 0; kk < 2; ++kk)
          acc[mi][2 + ni] = mfma16(af0[mi][kk], bf1[ni][kk], acc[mi][2 + ni]);
    __builtin_amdgcn_s_setprio(0);
    BARRIER();
    // P3: read A strip1 ; stage B1(t+2) ; MFMA (s1,s1)
#pragma unroll
    for (int mi = 0; mi < 4; ++mi) {
      const int rb = (128 + wr * 64 + mi * 16 + c16) * 128;
      af1[mi][0] = *(const bf16x8*)(Ac + rb + k0off);
      af1[mi][1] = *(const bf16x8*)(Ac + rb + k1off);
    }
    if (st) SB(buf, 1, t + 2);
    BARRIER(); LGKM0();
    __builtin_amdgcn_s_setprio(1);
#pragma unroll
    for (int mi = 0; mi < 4; ++mi)
#pragma unroll
      for (int ni = 0; ni < 2; ++ni)
#pragma unroll
        for (int kk = 0; kk < 2; ++kk)
          acc[4 + mi][2 + ni] = mfma16(af1[mi][kk], bf1[ni][kk], acc[4 + mi][2 + ni]);
    __builtin_amdgcn_s_setprio(0);
    BARRIER();
    // P4: stage A0(t+2) ; MFMA (s1,s0) ; boundary vmcnt(6)
    if (st) SA(buf, 0, t + 2);
    BARRIER();
    __builtin_amdgcn_s_setprio(1);
#pragma unroll
    for (int mi = 0; mi < 4; ++mi)
#pragma unroll
      for (int ni = 0; ni < 2; ++ni)
#pragma unroll
        for (int kk = 0; kk < 2; ++kk)
          acc[4 + mi][ni] = mfma16(af1[mi][kk], bf0[ni][kk], acc[4 + mi][ni]);
    __builtin_amdgcn_s_setprio(0);
    if (st) { asm volatile("s_waitcnt vmcnt(6)" ::: "memory"); }
    else    { asm volatile("s_waitcnt vmcnt(0)" ::: "memory"); }
    BARRIER();
  }

#pragma unroll
  for (int mi = 0; mi < 8; ++mi) {
    const int arow = (mi < 4) ? (wr * 64 + mi * 16) : (128 + wr * 64 + (mi - 4) * 16);
#pragma unroll
    for (int ni = 0; ni < 4; ++ni) {
      const int bcol = (ni < 2) ? (wc * 32 + ni * 16) : (128 + wc * 32 + (ni - 2) * 16);
#pragma unroll
      for (int r = 0; r < 4; ++r) {
        const int row = m0 + arow + g * 4 + r;
        const int col = n0 + bcol + c16;
        const float v = acc[mi][ni][r];
        if constexpr (EPI == 2) {
          const float t2 = v + e0[col];
          const float ge = 0.5f * t2 * (1.0f + erff(t2 * 0.7071067811865476f));
          o0[(size_t)row * N + col] = f2bf(ge);
        } else {
          const size_t idx = (size_t)row * N + col;
          fo[idx] = (EPI == 1) ? (e0[idx] + v) : (e1[idx] + v + e0[col]);
        }
      }
    }
  }
}

// ======== 128x128 GEMM, BK=64, swizzled LDS, natural block order ============
// EPI 0: QKV scatter — Q/K/V all bounce through LDS for coalesced stores
//        (Q pre-scaled by log2(e)/sqrt(hd) for base-2 softmax)
// EPI 1: +residual(x f32) -> bf16 x2        (o0 = x2 bf16, e0 = x)
// EPI 2: +bias,GELU -> bf16
// EPI 3: +bias+residual(x2 bf16) -> f32 out (rb = x2 bf16, e0 = bias)
template <int EPI>
__global__ __launch_bounds__(256, 2) void gemm128(
    const unsigned short* __restrict__ A, const unsigned short* __restrict__ Bt,
    int M, int N, int K,
    unsigned short* __restrict__ o0, unsigned short* __restrict__ o1,
    unsigned short* __restrict__ o2, float* __restrict__ fo,
    const float* __restrict__ e0, const unsigned short* __restrict__ rb) {
  __shared__ __attribute__((aligned(16))) unsigned short SM[4][128 * 64];
  const int tid = threadIdx.x;
  const int wid = tid >> 6, lane = tid & 63;
  const int m0 = blockIdx.y * 128, n0 = blockIdx.x * 128;
  const int wr = wid >> 1, wc = wid & 1;
  const int c16 = lane & 15, g = lane >> 4;

  const unsigned short *ap[4], *bp[4];
  int dsto[4];
#pragma unroll
  for (int j = 0; j < 4; ++j) {
    const int c = tid + j * 256;
    const int r = c >> 3, s = ((c & 7) ^ (r & 7)) * 8;
    ap[j] = A + (size_t)(m0 + r) * K + s;
    bp[j] = Bt + (size_t)(n0 + r) * K + s;
    dsto[j] = c * 8;
  }
  auto SA = [&](int buf, int kt) {
#pragma unroll
    for (int j = 0; j < 4; ++j) gload16(ap[j] + kt * 64, &SM[buf][dsto[j]]);
  };
  auto SB = [&](int buf, int kt) {
#pragma unroll
    for (int j = 0; j < 4; ++j) gload16(bp[j] + kt * 64, &SM[2 + buf][dsto[j]]);
  };

  const int swz   = (c16 & 7) << 4;
  const int k0off = (g * 16) ^ swz;
  const int k1off = (64 + g * 16) ^ swz;

  f32x4 acc[4][4];
#pragma unroll
  for (int i = 0; i < 4; i++)
#pragma unroll
    for (int j = 0; j < 4; j++) acc[i][j] = f32x4{0.f, 0.f, 0.f, 0.f};

  bf16x8 af[4][2], bfm[4][2];

  const int NT = K >> 6;
  SA(0, 0); SB(0, 0);
  __syncthreads();

  for (int t = 0; t < NT; ++t) {
    const int buf = t & 1;
    const char* Ac = (const char*)SM[buf];
    const char* Bc = (const char*)SM[2 + buf];
    if (t + 1 < NT) { SA(buf ^ 1, t + 1); SB(buf ^ 1, t + 1); }
#pragma unroll
    for (int mi = 0; mi < 4; ++mi) {
      const int rb2 = (wr * 64 + mi * 16 + c16) * 128;
      af[mi][0] = *(const bf16x8*)(Ac + rb2 + k0off);
      af[mi][1] = *(const bf16x8*)(Ac + rb2 + k1off);
    }
#pragma unroll
    for (int ni = 0; ni < 4; ++ni) {
      const int rb2 = (wc * 64 + ni * 16 + c16) * 128;
      bfm[ni][0] = *(const bf16x8*)(Bc + rb2 + k0off);
      bfm[ni][1] = *(const bf16x8*)(Bc + rb2 + k1off);
    }
    __builtin_amdgcn_s_setprio(1);
#pragma unroll
    for (int mi = 0; mi < 4; ++mi)
#pragma unroll
      for (int ni = 0; ni < 4; ++ni)
#pragma unroll
        for (int kk = 0; kk < 2; ++kk)
          acc[mi][ni] = mfma16(af[mi][kk], bfm[ni][kk], acc[mi][ni]);
    __builtin_amdgcn_s_setprio(0);
    __syncthreads();
  }

  if constexpr (EPI == 0) {
    const int which = n0 >> 11;       // block-uniform: 0=Q 1=K 2=V
    const int b  = m0 >> 11, s0v = m0 & 2047;
    const int hh = (n0 & 2047) >> 7;
    if (which == 2) {
      // V: transpose bounce -> [hd][s] coalesced stores (vT layout)
      unsigned short* Ls = &SM[0][0];           // 128 x 136
#pragma unroll
      for (int mi = 0; mi < 4; ++mi)
#pragma unroll
        for (int ni = 0; ni < 4; ++ni)
#pragma unroll
          for (int r = 0; r < 4; ++r) {
            const int s_loc = wr * 64 + mi * 16 + g * 4 + r;
            const int d_loc = wc * 64 + ni * 16 + c16;
            Ls[d_loc * 136 + s_loc] = f2bf(acc[mi][ni][r]);
          }
      __syncthreads();
      const size_t base = (size_t)(b * NH + hh) * HD * (size_t)SEQ;
#pragma unroll
      for (int it2 = 0; it2 < 2; ++it2) {
        const int hd = it2 * 64 + (tid >> 2);
        const int sc = (tid & 3) * 32;
#pragma unroll
        for (int j = 0; j < 4; ++j) {
          uint4 vv = *(const uint4*)&Ls[hd * 136 + sc + j * 8];
          *(uint4*)&o2[base + (size_t)hd * SEQ + s0v + sc + j * 8] = vv;
        }
      }
    } else {
      // Q/K: straight bounce -> [s][hd] coalesced stores (row-major layout)
      unsigned short* Ls = &SM[0][0];           // 128 x 136
      const float qsc = (which == 0) ? 0.127517434f : 1.0f;  // log2e/sqrt(128)
#pragma unroll
      for (int mi = 0; mi < 4; ++mi)
#pragma unroll
        for (int ni = 0; ni < 4; ++ni)
#pragma unroll
          for (int r = 0; r < 4; ++r) {
            const int s_loc = wr * 64 + mi * 16 + g * 4 + r;
            const int d_loc = wc * 64 + ni * 16 + c16;
            Ls[s_loc * 136 + d_loc] = f2bf(acc[mi][ni][r] * qsc);
          }
      __syncthreads();
      unsigned short* dst = (which == 0) ? o0 : o1;
      const size_t base = ((size_t)(b * NH + hh) * SEQ + s0v) * HD;
      const int srow = tid >> 1, soff = (tid & 1) * 64;
#pragma unroll
      for (int j = 0; j < 8; ++j) {
        uint4 vv = *(const uint4*)&Ls[srow * 136 + soff + j * 8];
        *(uint4*)&dst[base + (size_t)srow * HD + soff + j * 8] = vv;
      }
    }
  } else {
#pragma unroll
    for (int mi = 0; mi < 4; ++mi) {
#pragma unroll
      for (int ni = 0; ni < 4; ++ni) {
#pragma unroll
        for (int r = 0; r < 4; ++r) {
          const int row = m0 + wr * 64 + mi * 16 + g * 4 + r;
          const int col = n0 + wc * 64 + ni * 16 + c16;
          const float v = acc[mi][ni][r];
          const size_t idx = (size_t)row * N + col;
          if constexpr (EPI == 2) {
            const float t2 = v + e0[col];
            const float ge = 0.5f * t2 * (1.0f + erff(t2 * 0.7071067811865476f));
            o0[idx] = f2bf(ge);
          } else if constexpr (EPI == 1) {
            o0[idx] = f2bf(e0[idx] + v);            // x2 (bf16) = x + attn_out
          } else {
            fo[idx] = bf2f(rb[idx]) + v + e0[col];  // out = x2 + ffn + bias
          }
        }
      }
    }
  }
}

// ---------------- flash attention (R16: dbuf + defer-rescale + exp2 + lazy l)
__global__ __launch_bounds__(256, 2) void attn_kernel(
    const unsigned short* __restrict__ q, const unsigned short* __restrict__ k,
    const unsigned short* __restrict__ vT, unsigned short* __restrict__ out) {
  __shared__ __attribute__((aligned(16))) unsigned short Ks[2][64 * 128];
  __shared__ __attribute__((aligned(16))) unsigned short Vs[2][128 * 64];
  __shared__ __attribute__((aligned(16))) unsigned short Ps[4 * 32 * 64];
  const int tid = threadIdx.x, wid = tid >> 6, lane = tid & 63;
  const int c16 = lane & 15, g = lane >> 4;
  const int vbk = xcd_swz(blockIdx.x, 512);
  const int qt = vbk & 15, h = (vbk >> 4) & 15, b = vbk >> 8;
  const int q0 = qt * 128;
  const unsigned short* qb = q + (size_t)(b * NH + h) * SEQ * HD;
  const unsigned short* kb = k + (size_t)(b * NH + h) * SEQ * HD;
  const unsigned short* vb = vT + (size_t)(b * NH + h) * HD * SEQ;

  bf16x8 aq[2][4];
#pragma unroll
  for (int mi = 0; mi < 2; mi++)
#pragma unroll
    for (int ks = 0; ks < 4; ks++)
      aq[mi][ks] = *(const bf16x8*)(qb + (size_t)(q0 + wid * 32 + mi * 16 + c16) * HD +
                                    ks * 32 + g * 8);

  f32x4 o[2][8] = {};
  float mrow[2][4], lrow[2][4];
#pragma unroll
  for (int mi = 0; mi < 2; mi++)
#pragma unroll
    for (int r = 0; r < 4; r++) { mrow[mi][r] = -1e30f; lrow[mi][r] = 0.f; }

  const int kRowB = tid >> 4;
  const int kChk  = (tid & 15) ^ (kRowB & 7);
  const int vRowB = tid >> 3;
  const int vChk  = (tid & 7) ^ (vRowB & 7);
  char* PsW = (char*)Ps + wid * 4096;

  auto STAGE = [&](int buf, int kv0) {
#pragma unroll
    for (int seg = 0; seg < 4; seg++) {
      gload16(kb + (size_t)(kv0 + seg * 16 + kRowB) * HD + kChk * 8,
              &Ks[buf][wid * 512 + seg * 2048]);
      gload16(vb + (size_t)(seg * 32 + vRowB) * SEQ + kv0 + vChk * 8,
              &Vs[buf][wid * 512 + seg * 2048]);
    }
  };

  STAGE(0, 0);
  __syncthreads();

  const int NIT = SEQ / 64;
  for (int it = 0; it < NIT; ++it) {
    const int cur = it & 1;
    if (it + 1 < NIT) STAGE(cur ^ 1, (it + 1) * 64);
    const char* Kc = (const char*)&Ks[cur][0];
    const char* Vc = (const char*)&Vs[cur][0];

    f32x4 sc[2][4] = {};
#pragma unroll
    for (int ks = 0; ks < 4; ks++) {
#pragma unroll
      for (int ni = 0; ni < 4; ni++) {
        const int kr = ni * 16 + c16;
        const int lin = kr * 256 + ks * 64 + g * 16;
        bf16x8 bk = *(const bf16x8*)(Kc + (lin ^ ((kr & 7) << 4)));
        sc[0][ni] = mfma16(aq[0][ks], bk, sc[0][ni]);
        sc[1][ni] = mfma16(aq[1][ks], bk, sc[1][ni]);
      }
    }

#pragma unroll
    for (int mi = 0; mi < 2; mi++) {
#pragma unroll
      for (int r = 0; r < 4; r++) {
        float pm = fmaxf(fmaxf(sc[mi][0][r], sc[mi][1][r]),
                         fmaxf(sc[mi][2][r], sc[mi][3][r]));
        pm = fmaxf(pm, __shfl_xor(pm, 1));
        pm = fmaxf(pm, __shfl_xor(pm, 2));
        pm = fmaxf(pm, __shfl_xor(pm, 4));
        pm = fmaxf(pm, __shfl_xor(pm, 8));
        if (!__all(pm <= mrow[mi][r])) {
          const float mnew = fmaxf(mrow[mi][r], pm);
          const float scal = exp2f(mrow[mi][r] - mnew);
          mrow[mi][r] = mnew;
          lrow[mi][r] *= scal;
#pragma unroll
          for (int nj = 0; nj < 8; nj++) o[mi][nj][r] *= scal;
        }
        float rs = 0.f;
        const int prow = mi * 16 + g * 4 + r;
#pragma unroll
        for (int ni = 0; ni < 4; ni++) {
          const float p = exp2f(sc[mi][ni][r] - mrow[mi][r]);
          rs += p;
          const int lin = prow * 128 + (ni * 16 + c16) * 2;
          *(unsigned short*)(PsW + (lin ^ ((prow & 7) << 4))) = f2bf(p);
        }
        lrow[mi][r] += rs;
      }
    }

#pragma unroll
    for (int ks2 = 0; ks2 < 2; ks2++) {
      bf16x8 pa[2];
#pragma unroll
      for (int mi = 0; mi < 2; mi++) {
        const int pr = mi * 16 + c16;
        const int lin = pr * 128 + ks2 * 64 + g * 16;
        pa[mi] = *(const bf16x8*)(PsW + (lin ^ ((pr & 7) << 4)));
      }
#pragma unroll
      for (int nj = 0; nj < 8; nj++) {
        const int vr = nj * 16 + c16;
        const int lin = vr * 128 + ks2 * 64 + g * 16;
        bf16x8 bv = *(const bf16x8*)(Vc + (lin ^ ((vr & 7) << 4)));
        o[0][nj] = mfma16(pa[0], bv, o[0][nj]);
        o[1][nj] = mfma16(pa[1], bv, o[1][nj]);
      }
    }
    __syncthreads();
  }

#pragma unroll
  for (int mi = 0; mi < 2; mi++)
#pragma unroll
    for (int r = 0; r < 4; r++) {
      float l = lrow[mi][r];
      l += __shfl_xor(l, 1);
      l += __shfl_xor(l, 2);
      l += __shfl_xor(l, 4);
      l += __shfl_xor(l, 8);
      const float inv = 1.0f / l;
      const int s = q0 + wid * 32 + mi * 16 + g * 4 + r;
#pragma unroll
      for (int nj = 0; nj < 8; nj++)
        out[((size_t)(b * SEQ + s)) * DM + h * HD + nj * 16 + c16] =
            f2bf(o[mi][nj][r] * inv);
    }
}

// ---------------- launcher ---------------------------------------------------
extern "C" void kernel_launch(void* const* d_in, const int* in_sizes, int n_in,
                              void* d_out, int out_size, void* d_ws, size_t ws_size,
                              hipStream_t stream) {
  const float* x  = (const float*)d_in[0];
  const float* wq = (const float*)d_in[1];
  const float* wk = (const float*)d_in[2];
  const float* wv = (const float*)d_in[3];
  const float* wo = (const float*)d_in[4];
  const float* w1 = (const float*)d_in[5];
  const float* b1 = (const float*)d_in[6];
  const float* w2 = (const float*)d_in[7];
  const float* b2 = (const float*)d_in[8];
  const float* g1 = (const float*)d_in[9];
  const float* be1 = (const float*)d_in[10];
  const float* g2 = (const float*)d_in[11];
  const float* be2 = (const float*)d_in[12];

  char* ws = (char*)d_ws;
  unsigned short* wqkvT = (unsigned short*)(ws + 0);
  unsigned short* woT   = (unsigned short*)(ws + 25165824);
  unsigned short* w1T   = (unsigned short*)(ws + 33554432);
  unsigned short* w2T   = (unsigned short*)(ws + 67108864);
  unsigned short* x2b   = (unsigned short*)(ws + 100663296);  // x2 residual, bf16
  unsigned short* hbuf  = (unsigned short*)(ws + 134217728);
  unsigned short* qbuf  = (unsigned short*)(ws + 150994944);
  unsigned short* kbuf  = (unsigned short*)(ws + 167772160);
  unsigned short* vtbuf = (unsigned short*)(ws + 184549376);
  unsigned short* ffh   = (unsigned short*)(ws + 150994944);

  transpose_cast4<<<dim3(32, 32, 4), 256, 0, stream>>>(wq, wk, wv, wo, wqkvT, woT);
  transpose_cast<<<dim3(128, 32), 256, 0, stream>>>(w1, w1T, 2048, 8192);
  transpose_cast<<<dim3(32, 128), 256, 0, stream>>>(w2, w2T, 8192, 2048);

  ln_kernel<<<NTOK, 256, 0, stream>>>(x, g1, be1, hbuf);

  // QKV: gemm128 natural, 1536 blocks; Q/K/V all via LDS-bounce epilogues
  gemm128<0><<<dim3(48, 32), 256, 0, stream>>>(
      hbuf, wqkvT, NTOK, 6144, 2048, qbuf, kbuf, vtbuf, nullptr, nullptr, nullptr);

  attn_kernel<<<512, 256, 0, stream>>>(qbuf, kbuf, vtbuf, hbuf);

  // WO: gemm128, 512 blocks; writes bf16 x2 = x + attn_out
  gemm128<1><<<dim3(16, 32), 256, 0, stream>>>(
      hbuf, woT, NTOK, 2048, 2048, x2b, nullptr, nullptr, nullptr, x, nullptr);

  ln_kernel_b<<<NTOK, 256, 0, stream>>>(x2b, g2, be2, hbuf);

  // FFN1: gemm256 8-phase v2 (best measured), 512 blocks
  gemm256<2><<<dim3(32, 16), 512, 0, stream>>>(
      hbuf, w1T, NTOK, DFF, 2048, ffh, nullptr, nullptr, nullptr, b1, nullptr);

  // FFN2: gemm128, 512 blocks; out = x2(bf16) + ffn + bias -> f32 d_out
  gemm128<3><<<dim3(16, 32), 256, 0, stream>>>(
      ffh, w2T, NTOK, 2048, DFF, nullptr, nullptr, nullptr, (float*)d_out, b2, x2b);
}

// Round 22
// 615.379 us; speedup vs baseline: 1.0049x; 1.0049x over previous
//
#include <hip/hip_runtime.h>
#include <cstdint>
#include <cstddef>

#define DM   2048
#define NH   16
#define HD   128
#define DFF  8192
#define SEQ  2048
#define NB   2
#define NTOK (NB * SEQ)

using bf16x8 = __attribute__((ext_vector_type(8))) __bf16;
using f32x4  = __attribute__((ext_vector_type(4))) float;

__device__ __forceinline__ unsigned short f2bf(float f) {
  unsigned int u = __float_as_uint(f);
  u += 0x7fffu + ((u >> 16) & 1u);
  return (unsigned short)(u >> 16);
}
__device__ __forceinline__ float bf2f(unsigned short u) {
  return __uint_as_float((unsigned int)u << 16);
}

__device__ __forceinline__ void gload16(const void* g, void* l) {
  __builtin_amdgcn_global_load_lds(
      (const __attribute__((address_space(1))) unsigned int*)g,
      (__attribute__((address_space(3))) unsigned int*)l, 16, 0, 0);
}

__device__ __forceinline__ f32x4 mfma16(bf16x8 a, bf16x8 b, f32x4 c) {
  return __builtin_amdgcn_mfma_f32_16x16x32_bf16(a, b, c, 0, 0, 0);
}

#define BARRIER() asm volatile("s_barrier" ::: "memory")
#define LGKM0()   asm volatile("s_waitcnt lgkmcnt(0)" ::: "memory")

// XCD swizzle: kept ONLY for attention (chunk of 64 blocks = 4 whole heads =
// 4 MB K/V per XCD L2). On GEMMs it duplicated B across XCDs -> natural order.
__device__ __forceinline__ int xcd_swz(int hb, int nwg) {
  return (hb & 7) * (nwg >> 3) + (hb >> 3);
}

// ---------------- transpose + cast fp32 -> bf16, 64x64 tiles ----------------
__device__ __forceinline__ void tc64_body(
    const float* __restrict__ src, unsigned short* __restrict__ dst,
    int R, int C, int r0, int c0) {
  __shared__ float tile[64][65];
  const int t = threadIdx.x;
#pragma unroll
  for (int j = 0; j < 4; ++j) {
    const int c = t + j * 256;
    const int row = c >> 4, col = (c & 15) * 4;
    float4 v = *(const float4*)(src + (size_t)(r0 + row) * C + c0 + col);
    tile[row][col] = v.x; tile[row][col + 1] = v.y;
    tile[row][col + 2] = v.z; tile[row][col + 3] = v.w;
  }
  __syncthreads();
#pragma unroll
  for (int j = 0; j < 4; ++j) {
    const int c = t + j * 256;
    const int drow = c >> 4, scol = (c & 15) * 4;
    union { unsigned short u[4]; ushort4 v; } pk;
    pk.u[0] = f2bf(tile[scol][drow]);
    pk.u[1] = f2bf(tile[scol + 1][drow]);
    pk.u[2] = f2bf(tile[scol + 2][drow]);
    pk.u[3] = f2bf(tile[scol + 3][drow]);
    *(ushort4*)(dst + (size_t)(c0 + drow) * R + r0 + scol) = pk.v;
  }
}

__global__ __launch_bounds__(256) void transpose_cast(
    const float* __restrict__ src, unsigned short* __restrict__ dst, int R, int C) {
  tc64_body(src, dst, R, C, blockIdx.y * 64, blockIdx.x * 64);
}

__global__ __launch_bounds__(256) void transpose_cast4(
    const float* __restrict__ wq, const float* __restrict__ wk,
    const float* __restrict__ wv, const float* __restrict__ wo,
    unsigned short* __restrict__ dqkv, unsigned short* __restrict__ dwo) {
  const int z = blockIdx.z;
  const float* src = (z == 0) ? wq : (z == 1) ? wk : (z == 2) ? wv : wo;
  unsigned short* dst = (z < 3) ? (dqkv + (size_t)z * 2048 * 2048) : dwo;
  tc64_body(src, dst, 2048, 2048, blockIdx.y * 64, blockIdx.x * 64);
}

// ---------------- layernorm fp32 -> bf16 ------------------------------------
__global__ __launch_bounds__(256) void ln_kernel(
    const float* __restrict__ x, const float* __restrict__ gam,
    const float* __restrict__ bet, unsigned short* __restrict__ out) {
  const int row = blockIdx.x, tid = threadIdx.x;
  const float* xr = x + (size_t)row * DM;
  float4 a = *(const float4*)(xr + tid * 8);
  float4 b = *(const float4*)(xr + tid * 8 + 4);
  float s  = a.x + a.y + a.z + a.w + b.x + b.y + b.z + b.w;
  float s2 = a.x*a.x + a.y*a.y + a.z*a.z + a.w*a.w +
             b.x*b.x + b.y*b.y + b.z*b.z + b.w*b.w;
#pragma unroll
  for (int off = 32; off > 0; off >>= 1) {
    s  += __shfl_xor(s, off);
    s2 += __shfl_xor(s2, off);
  }
  __shared__ float red[8];
  const int wid = tid >> 6;
  if ((tid & 63) == 0) { red[wid] = s; red[4 + wid] = s2; }
  __syncthreads();
  s  = red[0] + red[1] + red[2] + red[3];
  s2 = red[4] + red[5] + red[6] + red[7];
  const float mean = s * (1.0f / DM);
  const float var  = s2 * (1.0f / DM) - mean * mean;
  const float rstd = rsqrtf(var + 1e-5f);
  float4 g0 = *(const float4*)(gam + tid * 8);
  float4 g1 = *(const float4*)(gam + tid * 8 + 4);
  float4 e0 = *(const float4*)(bet + tid * 8);
  float4 e1 = *(const float4*)(bet + tid * 8 + 4);
  union { unsigned short u[8]; uint4 v; } pk;
  const float* av = (const float*)&a; const float* bv = (const float*)&b;
  const float* gv0 = (const float*)&g0; const float* gv1 = (const float*)&g1;
  const float* ev0 = (const float*)&e0; const float* ev1 = (const float*)&e1;
#pragma unroll
  for (int j = 0; j < 4; j++) pk.u[j]     = f2bf((av[j] - mean) * rstd * gv0[j] + ev0[j]);
#pragma unroll
  for (int j = 0; j < 4; j++) pk.u[4 + j] = f2bf((bv[j] - mean) * rstd * gv1[j] + ev1[j]);
  *(uint4*)(out + (size_t)row * DM + tid * 8) = pk.v;
}

// ---------------- layernorm bf16 -> bf16 (x2 residual stream) ---------------
__global__ __launch_bounds__(256) void ln_kernel_b(
    const unsigned short* __restrict__ x, const float* __restrict__ gam,
    const float* __restrict__ bet, unsigned short* __restrict__ out) {
  const int row = blockIdx.x, tid = threadIdx.x;
  const unsigned short* xr = x + (size_t)row * DM;
  union { unsigned short u[8]; uint4 v; } in;
  in.v = *(const uint4*)(xr + tid * 8);
  float xv[8];
#pragma unroll
  for (int j = 0; j < 8; ++j) xv[j] = bf2f(in.u[j]);
  float s = 0.f, s2 = 0.f;
#pragma unroll
  for (int j = 0; j < 8; ++j) { s += xv[j]; s2 += xv[j] * xv[j]; }
#pragma unroll
  for (int off = 32; off > 0; off >>= 1) {
    s  += __shfl_xor(s, off);
    s2 += __shfl_xor(s2, off);
  }
  __shared__ float red[8];
  const int wid = tid >> 6;
  if ((tid & 63) == 0) { red[wid] = s; red[4 + wid] = s2; }
  __syncthreads();
  s  = red[0] + red[1] + red[2] + red[3];
  s2 = red[4] + red[5] + red[6] + red[7];
  const float mean = s * (1.0f / DM);
  const float var  = s2 * (1.0f / DM) - mean * mean;
  const float rstd = rsqrtf(var + 1e-5f);
  float4 g0 = *(const float4*)(gam + tid * 8);
  float4 g1 = *(const float4*)(gam + tid * 8 + 4);
  float4 e0 = *(const float4*)(bet + tid * 8);
  float4 e1 = *(const float4*)(bet + tid * 8 + 4);
  const float* gv0 = (const float*)&g0; const float* gv1 = (const float*)&g1;
  const float* ev0 = (const float*)&e0; const float* ev1 = (const float*)&e1;
  union { unsigned short u[8]; uint4 v; } pk;
#pragma unroll
  for (int j = 0; j < 4; j++) pk.u[j]     = f2bf((xv[j] - mean) * rstd * gv0[j] + ev0[j]);
#pragma unroll
  for (int j = 0; j < 4; j++) pk.u[4 + j] = f2bf((xv[4 + j] - mean) * rstd * gv1[j] + ev1[j]);
  *(uint4*)(out + (size_t)row * DM + tid * 8) = pk.v;
}

// ======== 256x256 8-phase GEMM v2 (best measured: 175 us / 790 TF on FFN1) ==
template <int EPI>
__global__ __launch_bounds__(512, 2) void gemm256(
    const unsigned short* __restrict__ A, const unsigned short* __restrict__ Bt,
    int M, int N, int K,
    unsigned short* __restrict__ o0, unsigned short* __restrict__ o1,
    unsigned short* __restrict__ o2, float* __restrict__ fo,
    const float* __restrict__ e0, const float* __restrict__ e1) {
  __shared__ __attribute__((aligned(16))) unsigned short As[2][256 * 64];
  __shared__ __attribute__((aligned(16))) unsigned short Bs[2][256 * 64];
  const int tid = threadIdx.x;
  const int wid = tid >> 6, lane = tid & 63;
  const int wr = wid >> 2, wc = wid & 3;
  const int c16 = lane & 15, g = lane >> 4;
  const int m0 = blockIdx.y * 256, n0 = blockIdx.x * 256;

  const int c0 = tid, c1 = tid + 512;
  const int r0_ = c0 >> 3, s0_ = ((c0 & 7) ^ (r0_ & 7)) * 8;
  const int r1_ = c1 >> 3, s1_ = ((c1 & 7) ^ (r1_ & 7)) * 8;
  const unsigned short* a0p = A + (size_t)(m0 + r0_) * K + s0_;
  const unsigned short* a1p = A + (size_t)(m0 + r1_) * K + s1_;
  const unsigned short* b0p = Bt + (size_t)(n0 + r0_) * K + s0_;
  const unsigned short* b1p = Bt + (size_t)(n0 + r1_) * K + s1_;
  const size_t hstep = (size_t)128 * K;

  auto SA = [&](int buf, int h, int kt) {
    gload16(a0p + h * hstep + kt * 64, &As[buf][h * 8192 + c0 * 8]);
    gload16(a1p + h * hstep + kt * 64, &As[buf][h * 8192 + c1 * 8]);
  };
  auto SB = [&](int buf, int h, int kt) {
    gload16(b0p + h * hstep + kt * 64, &Bs[buf][h * 8192 + c0 * 8]);
    gload16(b1p + h * hstep + kt * 64, &Bs[buf][h * 8192 + c1 * 8]);
  };

  const int swz   = (c16 & 7) << 4;
  const int k0off = (g * 16) ^ swz;
  const int k1off = (64 + g * 16) ^ swz;

  f32x4 acc[8][4];
#pragma unroll
  for (int i = 0; i < 8; i++)
#pragma unroll
    for (int j = 0; j < 4; j++) acc[i][j] = f32x4{0.f, 0.f, 0.f, 0.f};

  bf16x8 af0[4][2], af1[4][2], bf0[2][2], bf1[2][2];

  const int NT = K >> 6;
  SA(0, 0, 0); SA(0, 1, 0); SB(0, 0, 0); SB(0, 1, 0);
  SB(1, 0, 1); SB(1, 1, 1); SA(1, 0, 1);
  asm volatile("s_waitcnt vmcnt(6)" ::: "memory");
  BARRIER();

  for (int t = 0; t < NT; ++t) {
    const int buf = t & 1;
    const char* Ac = (const char*)As[buf];
    const char* Bc = (const char*)Bs[buf];
    const bool st = (t + 2) < NT;
    // P1: read A strip0 + B strip0 ; stage A1(t+1) -> buf^1 ; MFMA (s0,s0)
#pragma unroll
    for (int mi = 0; mi < 4; ++mi) {
      const int rb = (wr * 64 + mi * 16 + c16) * 128;
      af0[mi][0] = *(const bf16x8*)(Ac + rb + k0off);
      af0[mi][1] = *(const bf16x8*)(Ac + rb + k1off);
    }
#pragma unroll
    for (int ni = 0; ni < 2; ++ni) {
      const int rb = (wc * 32 + ni * 16 + c16) * 128;
      bf0[ni][0] = *(const bf16x8*)(Bc + rb + k0off);
      bf0[ni][1] = *(const bf16x8*)(Bc + rb + k1off);
    }
    if (t + 1 < NT) SA(buf ^ 1, 1, t + 1);
    BARRIER(); LGKM0();
    __builtin_amdgcn_s_setprio(1);
#pragma unroll
    for (int mi = 0; mi < 4; ++mi)
#pragma unroll
      for (int ni = 0; ni < 2; ++ni)
#pragma unroll
        for (int kk = 0; kk < 2; ++kk)
          acc[mi][ni] = mfma16(af0[mi][kk], bf0[ni][kk], acc[mi][ni]);
    __builtin_amdgcn_s_setprio(0);
    BARRIER();
    // P2: read B strip1 ; stage B0(t+2) ; MFMA (s0,s1)
#pragma unroll
    for (int ni = 0; ni < 2; ++ni) {
      const int rb = (128 + wc * 32 + ni * 16 + c16) * 128;
      bf1[ni][0] = *(const bf16x8*)(Bc + rb + k0off);
      bf1[ni][1] = *(const bf16x8*)(Bc + rb + k1off);
    }
    if (st) SB(buf, 0, t + 2);
    BARRIER(); LGKM0();
    __builtin_amdgcn_s_setprio(1);
#pragma unroll
    for (int mi = 0; mi < 4; ++mi)
#pragma unroll
      for (int ni = 0; ni < 2; ++ni)
#pragma unroll
        for (int kk = 0; kk < 2; ++kk)
          acc[mi][2 + ni] = mfma16(af0[mi][kk], bf1[ni][kk], acc[mi][2 + ni]);
    __builtin_amdgcn_s_setprio(0);
    BARRIER();
    // P3: read A strip1 ; stage B1(t+2) ; MFMA (s1,s1)
#pragma unroll
    for (int mi = 0; mi < 4; ++mi) {
      const int rb = (128 + wr * 64 + mi * 16 + c16) * 128;
      af1[mi][0] = *(const bf16x8*)(Ac + rb + k0off);
      af1[mi][1] = *(const bf16x8*)(Ac + rb + k1off);
    }
    if (st) SB(buf, 1, t + 2);
    BARRIER(); LGKM0();
    __builtin_amdgcn_s_setprio(1);
#pragma unroll
    for (int mi = 0; mi < 4; ++mi)
#pragma unroll
      for (int ni = 0; ni < 2; ++ni)
#pragma unroll
        for (int kk = 0; kk < 2; ++kk)
          acc[4 + mi][2 + ni] = mfma16(af1[mi][kk], bf1[ni][kk], acc[4 + mi][2 + ni]);
    __builtin_amdgcn_s_setprio(0);
    BARRIER();
    // P4: stage A0(t+2) ; MFMA (s1,s0) ; boundary vmcnt(6)
    if (st) SA(buf, 0, t + 2);
    BARRIER();
    __builtin_amdgcn_s_setprio(1);
#pragma unroll
    for (int mi = 0; mi < 4; ++mi)
#pragma unroll
      for (int ni = 0; ni < 2; ++ni)
#pragma unroll
        for (int kk = 0; kk < 2; ++kk)
          acc[4 + mi][ni] = mfma16(af1[mi][kk], bf0[ni][kk], acc[4 + mi][ni]);
    __builtin_amdgcn_s_setprio(0);
    if (st) { asm volatile("s_waitcnt vmcnt(6)" ::: "memory"); }
    else    { asm volatile("s_waitcnt vmcnt(0)" ::: "memory"); }
    BARRIER();
  }

#pragma unroll
  for (int mi = 0; mi < 8; ++mi) {
    const int arow = (mi < 4) ? (wr * 64 + mi * 16) : (128 + wr * 64 + (mi - 4) * 16);
#pragma unroll
    for (int ni = 0; ni < 4; ++ni) {
      const int bcol = (ni < 2) ? (wc * 32 + ni * 16) : (128 + wc * 32 + (ni - 2) * 16);
#pragma unroll
      for (int r = 0; r < 4; ++r) {
        const int row = m0 + arow + g * 4 + r;
        const int col = n0 + bcol + c16;
        const float v = acc[mi][ni][r];
        if constexpr (EPI == 2) {
          const float t2 = v + e0[col];
          const float ge = 0.5f * t2 * (1.0f + erff(t2 * 0.7071067811865476f));
          o0[(size_t)row * N + col] = f2bf(ge);
        } else {
          const size_t idx = (size_t)row * N + col;
          fo[idx] = (EPI == 1) ? (e0[idx] + v) : (e1[idx] + v + e0[col]);
        }
      }
    }
  }
}

// ======== 128x128 GEMM, BK=64, swizzled LDS, natural block order ============
// EPI 0: QKV scatter (Q pre-scaled by log2(e)/sqrt(hd); V via LDS bounce)
// EPI 1: +residual(x f32) -> bf16 x2        (o0 = x2 bf16, e0 = x)
// EPI 2: +bias,GELU -> bf16
// EPI 3: +bias+residual(x2 bf16) -> f32 out (rb = x2 bf16, e0 = bias)
template <int EPI>
__global__ __launch_bounds__(256, 2) void gemm128(
    const unsigned short* __restrict__ A, const unsigned short* __restrict__ Bt,
    int M, int N, int K,
    unsigned short* __restrict__ o0, unsigned short* __restrict__ o1,
    unsigned short* __restrict__ o2, float* __restrict__ fo,
    const float* __restrict__ e0, const unsigned short* __restrict__ rb) {
  __shared__ __attribute__((aligned(16))) unsigned short SM[4][128 * 64];
  const int tid = threadIdx.x;
  const int wid = tid >> 6, lane = tid & 63;
  const int m0 = blockIdx.y * 128, n0 = blockIdx.x * 128;
  const int wr = wid >> 1, wc = wid & 1;
  const int c16 = lane & 15, g = lane >> 4;

  const unsigned short *ap[4], *bp[4];
  int dsto[4];
#pragma unroll
  for (int j = 0; j < 4; ++j) {
    const int c = tid + j * 256;
    const int r = c >> 3, s = ((c & 7) ^ (r & 7)) * 8;
    ap[j] = A + (size_t)(m0 + r) * K + s;
    bp[j] = Bt + (size_t)(n0 + r) * K + s;
    dsto[j] = c * 8;
  }
  auto SA = [&](int buf, int kt) {
#pragma unroll
    for (int j = 0; j < 4; ++j) gload16(ap[j] + kt * 64, &SM[buf][dsto[j]]);
  };
  auto SB = [&](int buf, int kt) {
#pragma unroll
    for (int j = 0; j < 4; ++j) gload16(bp[j] + kt * 64, &SM[2 + buf][dsto[j]]);
  };

  const int swz   = (c16 & 7) << 4;
  const int k0off = (g * 16) ^ swz;
  const int k1off = (64 + g * 16) ^ swz;

  f32x4 acc[4][4];
#pragma unroll
  for (int i = 0; i < 4; i++)
#pragma unroll
    for (int j = 0; j < 4; j++) acc[i][j] = f32x4{0.f, 0.f, 0.f, 0.f};

  bf16x8 af[4][2], bfm[4][2];

  const int NT = K >> 6;
  SA(0, 0); SB(0, 0);
  __syncthreads();

  for (int t = 0; t < NT; ++t) {
    const int buf = t & 1;
    const char* Ac = (const char*)SM[buf];
    const char* Bc = (const char*)SM[2 + buf];
    if (t + 1 < NT) { SA(buf ^ 1, t + 1); SB(buf ^ 1, t + 1); }
#pragma unroll
    for (int mi = 0; mi < 4; ++mi) {
      const int rb2 = (wr * 64 + mi * 16 + c16) * 128;
      af[mi][0] = *(const bf16x8*)(Ac + rb2 + k0off);
      af[mi][1] = *(const bf16x8*)(Ac + rb2 + k1off);
    }
#pragma unroll
    for (int ni = 0; ni < 4; ++ni) {
      const int rb2 = (wc * 64 + ni * 16 + c16) * 128;
      bfm[ni][0] = *(const bf16x8*)(Bc + rb2 + k0off);
      bfm[ni][1] = *(const bf16x8*)(Bc + rb2 + k1off);
    }
    __builtin_amdgcn_s_setprio(1);
#pragma unroll
    for (int mi = 0; mi < 4; ++mi)
#pragma unroll
      for (int ni = 0; ni < 4; ++ni)
#pragma unroll
        for (int kk = 0; kk < 2; ++kk)
          acc[mi][ni] = mfma16(af[mi][kk], bfm[ni][kk], acc[mi][ni]);
    __builtin_amdgcn_s_setprio(0);
    __syncthreads();
  }

  if constexpr (EPI == 0) {
    const int which = n0 >> 11;       // block-uniform: 0=Q 1=K 2=V
    if (which == 2) {
      unsigned short* Ls = &SM[0][0];           // 128 x 136 bounce
#pragma unroll
      for (int mi = 0; mi < 4; ++mi)
#pragma unroll
        for (int ni = 0; ni < 4; ++ni)
#pragma unroll
          for (int r = 0; r < 4; ++r) {
            const int s_loc = wr * 64 + mi * 16 + g * 4 + r;
            const int d_loc = wc * 64 + ni * 16 + c16;
            Ls[d_loc * 136 + s_loc] = f2bf(acc[mi][ni][r]);
          }
      __syncthreads();
      const int b  = m0 >> 11, s0v = m0 & 2047;
      const int hh = (n0 & 2047) >> 7;
      const size_t base = (size_t)(b * NH + hh) * HD * (size_t)SEQ;
#pragma unroll
      for (int it2 = 0; it2 < 2; ++it2) {
        const int hd = it2 * 64 + (tid >> 2);
        const int sc = (tid & 3) * 32;
#pragma unroll
        for (int j = 0; j < 4; ++j) {
          uint4 vv = *(const uint4*)&Ls[hd * 136 + sc + j * 8];
          *(uint4*)&o2[base + (size_t)hd * SEQ + s0v + sc + j * 8] = vv;
        }
      }
    } else {
#pragma unroll
      for (int mi = 0; mi < 4; ++mi)
#pragma unroll
        for (int ni = 0; ni < 4; ++ni)
#pragma unroll
          for (int r = 0; r < 4; ++r) {
            const int row = m0 + wr * 64 + mi * 16 + g * 4 + r;
            const int col = n0 + wc * 64 + ni * 16 + c16;
            const float v = acc[mi][ni][r];
            const int b = row >> 11, s = row & 2047;
            const int d = col & 2047;
            const int hh = d >> 7, hd = d & 127;
            const size_t bh = (size_t)(b * NH + hh);
            // Q scale = 1/sqrt(128) * log2(e)  (base-2 softmax in attn)
            if (which == 0) o0[(bh * SEQ + s) * HD + hd] = f2bf(v * 0.127517434f);
            else            o1[(bh * SEQ + s) * HD + hd] = f2bf(v);
          }
    }
  } else {
#pragma unroll
    for (int mi = 0; mi < 4; ++mi) {
#pragma unroll
      for (int ni = 0; ni < 4; ++ni) {
#pragma unroll
        for (int r = 0; r < 4; ++r) {
          const int row = m0 + wr * 64 + mi * 16 + g * 4 + r;
          const int col = n0 + wc * 64 + ni * 16 + c16;
          const float v = acc[mi][ni][r];
          const size_t idx = (size_t)row * N + col;
          if constexpr (EPI == 2) {
            const float t2 = v + e0[col];
            const float ge = 0.5f * t2 * (1.0f + erff(t2 * 0.7071067811865476f));
            o0[idx] = f2bf(ge);
          } else if constexpr (EPI == 1) {
            o0[idx] = f2bf(e0[idx] + v);            // x2 (bf16) = x + attn_out
          } else {
            fo[idx] = bf2f(rb[idx]) + v + e0[col];  // out = x2 + ffn + bias
          }
        }
      }
    }
  }
}

// ---------------- flash attention (R16: dbuf + defer-rescale + exp2 + lazy l)
__global__ __launch_bounds__(256, 2) void attn_kernel(
    const unsigned short* __restrict__ q, const unsigned short* __restrict__ k,
    const unsigned short* __restrict__ vT, unsigned short* __restrict__ out) {
  __shared__ __attribute__((aligned(16))) unsigned short Ks[2][64 * 128];
  __shared__ __attribute__((aligned(16))) unsigned short Vs[2][128 * 64];
  __shared__ __attribute__((aligned(16))) unsigned short Ps[4 * 32 * 64];
  const int tid = threadIdx.x, wid = tid >> 6, lane = tid & 63;
  const int c16 = lane & 15, g = lane >> 4;
  const int vbk = xcd_swz(blockIdx.x, 512);
  const int qt = vbk & 15, h = (vbk >> 4) & 15, b = vbk >> 8;
  const int q0 = qt * 128;
  const unsigned short* qb = q + (size_t)(b * NH + h) * SEQ * HD;
  const unsigned short* kb = k + (size_t)(b * NH + h) * SEQ * HD;
  const unsigned short* vb = vT + (size_t)(b * NH + h) * HD * SEQ;

  bf16x8 aq[2][4];
#pragma unroll
  for (int mi = 0; mi < 2; mi++)
#pragma unroll
    for (int ks = 0; ks < 4; ks++)
      aq[mi][ks] = *(const bf16x8*)(qb + (size_t)(q0 + wid * 32 + mi * 16 + c16) * HD +
                                    ks * 32 + g * 8);

  f32x4 o[2][8] = {};
  float mrow[2][4], lrow[2][4];
#pragma unroll
  for (int mi = 0; mi < 2; mi++)
#pragma unroll
    for (int r = 0; r < 4; r++) { mrow[mi][r] = -1e30f; lrow[mi][r] = 0.f; }

  const int kRowB = tid >> 4;
  const int kChk  = (tid & 15) ^ (kRowB & 7);
  const int vRowB = tid >> 3;
  const int vChk  = (tid & 7) ^ (vRowB & 7);
  char* PsW = (char*)Ps + wid * 4096;

  auto STAGE = [&](int buf, int kv0) {
#pragma unroll
    for (int seg = 0; seg < 4; seg++) {
      gload16(kb + (size_t)(kv0 + seg * 16 + kRowB) * HD + kChk * 8,
              &Ks[buf][wid * 512 + seg * 2048]);
      gload16(vb + (size_t)(seg * 32 + vRowB) * SEQ + kv0 + vChk * 8,
              &Vs[buf][wid * 512 + seg * 2048]);
    }
  };

  STAGE(0, 0);
  __syncthreads();

  const int NIT = SEQ / 64;
  for (int it = 0; it < NIT; ++it) {
    const int cur = it & 1;
    if (it + 1 < NIT) STAGE(cur ^ 1, (it + 1) * 64);
    const char* Kc = (const char*)&Ks[cur][0];
    const char* Vc = (const char*)&Vs[cur][0];

    f32x4 sc[2][4] = {};
#pragma unroll
    for (int ks = 0; ks < 4; ks++) {
#pragma unroll
      for (int ni = 0; ni < 4; ni++) {
        const int kr = ni * 16 + c16;
        const int lin = kr * 256 + ks * 64 + g * 16;
        bf16x8 bk = *(const bf16x8*)(Kc + (lin ^ ((kr & 7) << 4)));
        sc[0][ni] = mfma16(aq[0][ks], bk, sc[0][ni]);
        sc[1][ni] = mfma16(aq[1][ks], bk, sc[1][ni]);
      }
    }

#pragma unroll
    for (int mi = 0; mi < 2; mi++) {
#pragma unroll
      for (int r = 0; r < 4; r++) {
        float pm = fmaxf(fmaxf(sc[mi][0][r], sc[mi][1][r]),
                         fmaxf(sc[mi][2][r], sc[mi][3][r]));
        pm = fmaxf(pm, __shfl_xor(pm, 1));
        pm = fmaxf(pm, __shfl_xor(pm, 2));
        pm = fmaxf(pm, __shfl_xor(pm, 4));
        pm = fmaxf(pm, __shfl_xor(pm, 8));
        if (!__all(pm <= mrow[mi][r])) {
          const float mnew = fmaxf(mrow[mi][r], pm);
          const float scal = exp2f(mrow[mi][r] - mnew);
          mrow[mi][r] = mnew;
          lrow[mi][r] *= scal;
#pragma unroll
          for (int nj = 0; nj < 8; nj++) o[mi][nj][r] *= scal;
        }
        float rs = 0.f;
        const int prow = mi * 16 + g * 4 + r;
#pragma unroll
        for (int ni = 0; ni < 4; ni++) {
          const float p = exp2f(sc[mi][ni][r] - mrow[mi][r]);
          rs += p;
          const int lin = prow * 128 + (ni * 16 + c16) * 2;
          *(unsigned short*)(PsW + (lin ^ ((prow & 7) << 4))) = f2bf(p);
        }
        lrow[mi][r] += rs;
      }
    }

#pragma unroll
    for (int ks2 = 0; ks2 < 2; ks2++) {
      bf16x8 pa[2];
#pragma unroll
      for (int mi = 0; mi < 2; mi++) {
        const int pr = mi * 16 + c16;
        const int lin = pr * 128 + ks2 * 64 + g * 16;
        pa[mi] = *(const bf16x8*)(PsW + (lin ^ ((pr & 7) << 4)));
      }
#pragma unroll
      for (int nj = 0; nj < 8; nj++) {
        const int vr = nj * 16 + c16;
        const int lin = vr * 128 + ks2 * 64 + g * 16;
        bf16x8 bv = *(const bf16x8*)(Vc + (lin ^ ((vr & 7) << 4)));
        o[0][nj] = mfma16(pa[0], bv, o[0][nj]);
        o[1][nj] = mfma16(pa[1], bv, o[1][nj]);
      }
    }
    __syncthreads();
  }

#pragma unroll
  for (int mi = 0; mi < 2; mi++)
#pragma unroll
    for (int r = 0; r < 4; r++) {
      float l = lrow[mi][r];
      l += __shfl_xor(l, 1);
      l += __shfl_xor(l, 2);
      l += __shfl_xor(l, 4);
      l += __shfl_xor(l, 8);
      const float inv = 1.0f / l;
      const int s = q0 + wid * 32 + mi * 16 + g * 4 + r;
#pragma unroll
      for (int nj = 0; nj < 8; nj++)
        out[((size_t)(b * SEQ + s)) * DM + h * HD + nj * 16 + c16] =
            f2bf(o[mi][nj][r] * inv);
    }
}

// ---------------- launcher ---------------------------------------------------
extern "C" void kernel_launch(void* const* d_in, const int* in_sizes, int n_in,
                              void* d_out, int out_size, void* d_ws, size_t ws_size,
                              hipStream_t stream) {
  const float* x  = (const float*)d_in[0];
  const float* wq = (const float*)d_in[1];
  const float* wk = (const float*)d_in[2];
  const float* wv = (const float*)d_in[3];
  const float* wo = (const float*)d_in[4];
  const float* w1 = (const float*)d_in[5];
  const float* b1 = (const float*)d_in[6];
  const float* w2 = (const float*)d_in[7];
  const float* b2 = (const float*)d_in[8];
  const float* g1 = (const float*)d_in[9];
  const float* be1 = (const float*)d_in[10];
  const float* g2 = (const float*)d_in[11];
  const float* be2 = (const float*)d_in[12];

  char* ws = (char*)d_ws;
  unsigned short* wqkvT = (unsigned short*)(ws + 0);
  unsigned short* woT   = (unsigned short*)(ws + 25165824);
  unsigned short* w1T   = (unsigned short*)(ws + 33554432);
  unsigned short* w2T   = (unsigned short*)(ws + 67108864);
  unsigned short* x2b   = (unsigned short*)(ws + 100663296);  // x2 residual, bf16
  unsigned short* hbuf  = (unsigned short*)(ws + 134217728);
  unsigned short* qbuf  = (unsigned short*)(ws + 150994944);
  unsigned short* kbuf  = (unsigned short*)(ws + 167772160);
  unsigned short* vtbuf = (unsigned short*)(ws + 184549376);
  unsigned short* ffh   = (unsigned short*)(ws + 150994944);

  transpose_cast4<<<dim3(32, 32, 4), 256, 0, stream>>>(wq, wk, wv, wo, wqkvT, woT);
  transpose_cast<<<dim3(128, 32), 256, 0, stream>>>(w1, w1T, 2048, 8192);
  transpose_cast<<<dim3(32, 128), 256, 0, stream>>>(w2, w2T, 8192, 2048);

  ln_kernel<<<NTOK, 256, 0, stream>>>(x, g1, be1, hbuf);

  // QKV: gemm128 natural, 1536 blocks; V-blocks use LDS-bounce V^T epilogue
  gemm128<0><<<dim3(48, 32), 256, 0, stream>>>(
      hbuf, wqkvT, NTOK, 6144, 2048, qbuf, kbuf, vtbuf, nullptr, nullptr, nullptr);

  attn_kernel<<<512, 256, 0, stream>>>(qbuf, kbuf, vtbuf, hbuf);

  // WO: gemm128, 512 blocks; writes bf16 x2 = x + attn_out
  gemm128<1><<<dim3(16, 32), 256, 0, stream>>>(
      hbuf, woT, NTOK, 2048, 2048, x2b, nullptr, nullptr, nullptr, x, nullptr);

  ln_kernel_b<<<NTOK, 256, 0, stream>>>(x2b, g2, be2, hbuf);

  // FFN1: gemm256 8-phase v2 (best measured), 512 blocks
  gemm256<2><<<dim3(32, 16), 512, 0, stream>>>(
      hbuf, w1T, NTOK, DFF, 2048, ffh, nullptr, nullptr, nullptr, b1, nullptr);

  // FFN2: gemm128, 512 blocks; out = x2(bf16) + ffn + bias -> f32 d_out
  gemm128<3><<<dim3(16, 32), 256, 0, stream>>>(
      ffh, w2T, NTOK, 2048, DFF, nullptr, nullptr, nullptr, (float*)d_out, b2, x2b);
}